// Round 1
// baseline (712.463 us; speedup 1.0000x reference)
//
#include <hip/hip_runtime.h>
#include <hip/hip_bf16.h>
#include <stdint.h>

typedef __attribute__((ext_vector_type(8))) short short8;
typedef __attribute__((ext_vector_type(4))) float floatx4;

#define AS1 __attribute__((address_space(1)))
#define AS3 __attribute__((address_space(3)))

// async global->LDS, 16B/lane. HW dest = wave-uniform base + lane*16, so every
// call site ensures its lane's dst == base + lane*16 (contiguous by lane).
__device__ __forceinline__ void async_copy16(const void* g, void* l) {
    __builtin_amdgcn_global_load_lds((const AS1 uint32_t*)(uintptr_t)g,
                                     (AS3 uint32_t*)(uintptr_t)l, 16, 0, 0);
}

// LDS swizzle: 64B rows of 4x16B chunks; logical chunk c of row r lives at
// phys chunk c ^ swz(r).  GEMM/sV use swz(r) = (r>>1)&3 (2-way aliasing, free).
// attn sK uses swz(r) = ((r>>1)&3) ^ ((r>>3)&3) so the PERMUTED fragment-row
// reads (rows {0-3,8-11,16-19,24-27}+c) also land 2-way instead of 4-way.

// load 8 f32 -> 8 bf16 packed
__device__ __forceinline__ short8 cvt8(const float* p) {
    float4 a = *(const float4*)p;
    float4 b = *(const float4*)(p + 4);
    union { short s[8]; short8 v; } u;
    __hip_bfloat16* h = (__hip_bfloat16*)u.s;
    h[0] = __float2bfloat16(a.x); h[1] = __float2bfloat16(a.y);
    h[2] = __float2bfloat16(a.z); h[3] = __float2bfloat16(a.w);
    h[4] = __float2bfloat16(b.x); h[5] = __float2bfloat16(b.y);
    h[6] = __float2bfloat16(b.z); h[7] = __float2bfloat16(b.w);
    return u.v;
}

// ---------------------------------------------------------------- cvt f32->bf16
__global__ __launch_bounds__(256) void cvt_bf16(const float* __restrict__ s,
                                                __hip_bfloat16* __restrict__ d, int n) {
    int i = ((int)blockIdx.x * 256 + (int)threadIdx.x) * 4;
    if (i >= n) return;
    const float4 v = *(const float4*)(s + i);
    ushort4 pk;
    __hip_bfloat16* ph = (__hip_bfloat16*)&pk;
    ph[0] = __float2bfloat16(v.x); ph[1] = __float2bfloat16(v.y);
    ph[2] = __float2bfloat16(v.z); ph[3] = __float2bfloat16(v.w);
    *(ushort4*)(d + i) = pk;
}

// ---------------------------------------------------------------- GEMM
// C = A @ Bt^T + bias. 128x128 tile, BK=32, 4 waves 2x2.
// A_ASYNC: 1 -> A is bf16, staged via global_load_lds; 0 -> A f32, sync cvt.
// B_ASYNC: same for B. STORE_MODE: 0 f32; 1 bf16; 2 bf16 V-transpose
//   (row=t,col=hid) -> Vt[(b*16+nh)*128+d][s], s=t>>2,b=t&3,nh=col>>7,d=col&127.
template <int A_ASYNC, int B_ASYNC, int STORE_MODE>
__global__ __launch_bounds__(256, 2) void gemm_k(const void* __restrict__ Av,
                                                 const void* __restrict__ Bv,
                                                 const float* __restrict__ bias,
                                                 void* __restrict__ Cv,
                                                 int M, int N, int K) {
    __shared__ __align__(16) __hip_bfloat16 sA[128 * 32];
    __shared__ __align__(16) __hip_bfloat16 sB[128 * 32];
    const int tid  = threadIdx.x;
    const int wave = tid >> 6, lane = tid & 63;
    const int quad = lane >> 4, l16 = lane & 15;
    const int m0 = blockIdx.x * 128, n0 = blockIdx.y * 128;
    const int wm = (wave >> 1) * 64, wn = (wave & 1) * 64;
    const int lrow   = lane >> 2;
    const int srcoff = (((lane & 3) ^ ((lane >> 3) & 3)) * 16);  // swizzled chunk, bytes
    const int dstoff = (lane & 3) * 16;                          // phys chunk, bytes
    const int swzq   = (quad ^ ((l16 >> 1) & 3)) * 16;           // fragment chunk, bytes

    floatx4 acc[4][4];
#pragma unroll
    for (int i = 0; i < 4; i++)
#pragma unroll
        for (int j = 0; j < 4; j++) acc[i][j] = (floatx4)0.0f;

    for (int k0 = 0; k0 < K; k0 += 32) {
        short8 va[2], vb[2];
#pragma unroll
        for (int c = 0; c < 2; ++c) {  // pre-barrier global loads for sync operands
            int r = wave * 32 + c * 16 + lrow;
            if (!A_ASYNC) va[c] = cvt8((const float*)Av + (size_t)(m0 + r) * K + k0 + (lane & 3) * 8);
            if (!B_ASYNC) vb[c] = cvt8((const float*)Bv + (size_t)(n0 + r) * K + k0 + (lane & 3) * 8);
        }
        __syncthreads();  // prior iteration's fragment reads done
#pragma unroll
        for (int c = 0; c < 2; ++c) {
            int r = wave * 32 + c * 16 + lrow;
            if (A_ASYNC)
                async_copy16((const char*)((const __hip_bfloat16*)Av + (size_t)(m0 + r) * K + k0) + srcoff,
                             (char*)sA + r * 64 + dstoff);
            else
                *(short8*)((char*)sA + r * 64 + srcoff) = va[c];
            if (B_ASYNC)
                async_copy16((const char*)((const __hip_bfloat16*)Bv + (size_t)(n0 + r) * K + k0) + srcoff,
                             (char*)sB + r * 64 + dstoff);
            else
                *(short8*)((char*)sB + r * 64 + srcoff) = vb[c];
        }
        __syncthreads();  // drain staging (vmcnt/lgkm before barrier)

        short8 af[4], bf[4];
#pragma unroll
        for (int i = 0; i < 4; i++)
            af[i] = *(const short8*)((const char*)sA + (wm + i * 16 + l16) * 64 + swzq);
#pragma unroll
        for (int j = 0; j < 4; j++)
            bf[j] = *(const short8*)((const char*)sB + (wn + j * 16 + l16) * 64 + swzq);
#pragma unroll
        for (int i = 0; i < 4; i++)
#pragma unroll
            for (int j = 0; j < 4; j++)
                acc[i][j] = __builtin_amdgcn_mfma_f32_16x16x32_bf16(af[i], bf[j], acc[i][j], 0, 0, 0);
    }

#pragma unroll
    for (int i = 0; i < 4; i++) {
#pragma unroll
        for (int j = 0; j < 4; j++) {
            int col  = n0 + wn + j * 16 + l16;
            float bv = bias[col];
#pragma unroll
            for (int r = 0; r < 4; ++r) {
                int row = m0 + wm + i * 16 + quad * 4 + r;  // C-layout: row=quad*4+reg
                float v = acc[i][j][r] + bv;
                if (STORE_MODE == 0) {
                    ((float*)Cv)[(size_t)row * N + col] = v;
                } else if (STORE_MODE == 1) {
                    ((__hip_bfloat16*)Cv)[(size_t)row * N + col] = __float2bfloat16(v);
                } else {
                    int s = row >> 2, b = row & 3, nh = col >> 7, d = col & 127;
                    ((__hip_bfloat16*)Cv)[((size_t)(b * 16 + nh) * 128 + d) * 2048 + s] =
                        __float2bfloat16(v);
                }
            }
        }
    }
}

// ---------------------------------------------------------------- RoPE (in-place)
__global__ __launch_bounds__(256) void rope_kernel(__hip_bfloat16* __restrict__ Q,
                                                   __hip_bfloat16* __restrict__ K) {
    const int PER = 8192 * 16 * 32;
    int idx = (int)blockIdx.x * 256 + (int)threadIdx.x;
    __hip_bfloat16* base = (idx < PER) ? Q : K;
    int i  = (idx < PER) ? idx : idx - PER;
    int p  = i & 31;
    int nh = (i >> 5) & 15;
    int t  = i >> 9;
    int s  = t >> 2;
    float inv = __expf(-(float)(p & 15) * 0.5756462732485115f);  // ln(10000)/16
    float ang = (float)s * inv;
    float c = cosf(ang), sn = sinf(ang);
    size_t off = (size_t)t * 2048 + nh * 128 + 2 * p;
    float x0 = __bfloat162float(base[off]);
    float x1 = __bfloat162float(base[off + 1]);
    base[off]     = __float2bfloat16(x0 * c - x1 * sn);
    base[off + 1] = __float2bfloat16(x0 * sn + x1 * c);
}

// ---------------------------------------------------------------- flash attention
// Qio [t][2048] (roped; O overwrites in place), Km [t][2048], Vt [bh][128][2048].
// Block (bh, qt): 128 q-rows, 64 kv/iter; wave owns 32 q rows (2 m-groups).
//
// Swapped-operand scheme: S^T = mfma(K, Q) with PERMUTED K-fragment rows
//   sigma(nt, i) = 32*(nt>>1) + 8*(i>>2) + 4*(nt&1) + (i&3)
// so after softmax each lane (quad,l16) holds exactly P[q=l16][kv=quad*8+0..7]
// of each 32-kv chunk == the B-fragment of O^T = mfma(V, P). No sP LDS, no
// cross-lane P traffic, and softmax reduces are 2 shfl steps (cross-quad only).
__global__ __launch_bounds__(256, 3) void attn_kernel(__hip_bfloat16* __restrict__ Qio,
                                                      const __hip_bfloat16* __restrict__ Km,
                                                      const __hip_bfloat16* __restrict__ Vt) {
    __shared__ __align__(16) __hip_bfloat16 sK[4][64][32];   // [d-chunk][kv][32d]
    __shared__ __align__(16) __hip_bfloat16 sV[2][128][32];  // [kv-chunk][d][32kv]
    const int tid  = threadIdx.x;
    const int wave = tid >> 6, lane = tid & 63;
    const int quad = lane >> 4, l16 = lane & 15;
    const int bh = blockIdx.x, b = bh >> 4, nh = bh & 15;
    const int qtl = 15 - (int)blockIdx.y;  // longest blocks first
    const int q0  = qtl * 128;
    const int lrow    = lane >> 2;
    const int dstoff  = (lane & 3) * 16;
    const int srcoffV = (((lane & 3) ^ ((lane >> 3) & 3)) * 16);  // sV: swz(r)=(r>>1)&3
    const int swzqV   = (quad ^ ((l16 >> 1) & 3)) * 16;
    const float scale = 0.08838834764831845f;  // 1/sqrt(128)

    // Q fragments (B-operand) in registers: rows wave*32+mg*16+l16, k = kk*32+quad*8+j
    short8 qf[2][4];
#pragma unroll
    for (int mg = 0; mg < 2; ++mg)
#pragma unroll
        for (int kk = 0; kk < 4; ++kk) {
            int qrow = wave * 32 + mg * 16 + l16;
            int t    = (q0 + qrow) * 4 + b;
            qf[mg][kk] = *(const short8*)(Qio + (size_t)t * 2048 + nh * 128 + kk * 32 + quad * 8);
        }

    float m_i[2], l_i[2];
#pragma unroll
    for (int mg = 0; mg < 2; ++mg) { m_i[mg] = -1e30f; l_i[mg] = 0.f; }
    floatx4 o_acc[2][8];  // O^T: d = nt*16 + quad*4 + r, q = l16 (per mg)
#pragma unroll
    for (int mg = 0; mg < 2; ++mg)
#pragma unroll
        for (int n = 0; n < 8; ++n) o_acc[mg][n] = (floatx4)0.0f;

    const int nk = 2 * qtl + 2;
    for (int kt = 0; kt < nk; ++kt) {
        __syncthreads();  // prior iter's sK/sV reads done
        {
#pragma unroll
            for (int c = 0; c < 4; ++c) {
                int krow = c * 16 + lrow;
                int swzK = ((krow >> 1) & 3) ^ ((krow >> 3) & 3);
                int srcK = ((lane & 3) ^ swzK) * 16;
                int t    = (kt * 64 + krow) * 4 + b;
                async_copy16((const char*)(Km + (size_t)t * 2048 + nh * 128 + wave * 32) + srcK,
                             (char*)&sK[wave][0][0] + krow * 64 + dstoff);
            }
            const int kc = wave >> 1, dh = (wave & 1) * 64;
#pragma unroll
            for (int c = 0; c < 4; ++c) {
                int d = dh + c * 16 + lrow;
                async_copy16((const char*)(Vt + ((size_t)bh * 128 + d) * 2048 + kt * 64 + kc * 32) + srcoffV,
                             (char*)&sV[kc][0][0] + d * 64 + dstoff);
            }
        }
        __syncthreads();  // drain staging

        // S^T = K Q^T (A = permuted K rows, B = Q). D[kv'][q] per 16x16 tile.
        floatx4 sacc[2][4];
#pragma unroll
        for (int mg = 0; mg < 2; ++mg)
#pragma unroll
            for (int n = 0; n < 4; ++n) sacc[mg][n] = (floatx4)0.0f;
#pragma unroll
        for (int nt = 0; nt < 4; ++nt) {
            int R    = (nt >> 1) * 32 + (l16 >> 2) * 8 + (nt & 1) * 4 + (l16 & 3);  // sigma row
            int swzK = ((R >> 1) & 3) ^ ((R >> 3) & 3);
            int off  = R * 64 + (quad ^ swzK) * 16;
#pragma unroll
            for (int kk = 0; kk < 4; ++kk) {
                short8 ak = *(const short8*)((const char*)&sK[kk][0][0] + off);
                sacc[0][nt] = __builtin_amdgcn_mfma_f32_16x16x32_bf16(ak, qf[0][kk], sacc[0][nt], 0, 0, 0);
                sacc[1][nt] = __builtin_amdgcn_mfma_f32_16x16x32_bf16(ak, qf[1][kk], sacc[1][nt], 0, 0, 0);
            }
        }

        // online softmax, fully in-register; P packed straight into B-fragments
        short8 ap[2][2];  // [mg][kv 32-chunk]
#pragma unroll
        for (int mg = 0; mg < 2; ++mg) {
            const int q     = q0 + wave * 32 + mg * 16 + l16;
            const bool dmask = (kt * 64 + 63) > (q0 + wave * 32 + mg * 16);
            float mx = -1e30f;
#pragma unroll
            for (int nt = 0; nt < 4; ++nt) {
                int kvb = kt * 64 + (nt >> 1) * 32 + quad * 8 + (nt & 1) * 4;  // sigma(nt, quad*4+r)
#pragma unroll
                for (int r = 0; r < 4; ++r) {
                    float v = sacc[mg][nt][r] * scale;
                    if (dmask && (kvb + r > q)) v = -1e30f;
                    sacc[mg][nt][r] = v;
                    mx = fmaxf(mx, v);
                }
            }
            mx = fmaxf(mx, __shfl_xor(mx, 16, 64));  // cross-quad only: q is lane-local
            mx = fmaxf(mx, __shfl_xor(mx, 32, 64));
            float mnew  = fmaxf(m_i[mg], mx);
            float alpha = __expf(m_i[mg] - mnew);
            m_i[mg] = mnew;
            float rs = 0.f;
#pragma unroll
            for (int nt = 0; nt < 4; ++nt)
#pragma unroll
                for (int r = 0; r < 4; ++r) {
                    float e = __expf(sacc[mg][nt][r] - mnew);
                    sacc[mg][nt][r] = e;
                    rs += e;
                }
            rs += __shfl_xor(rs, 16, 64);
            rs += __shfl_xor(rs, 32, 64);
            l_i[mg] = l_i[mg] * alpha + rs;
            // pack B-fragment: k-slot j<4 -> nt=2kc, j>=4 -> nt=2kc+1 (kv = quad*8+j)
#pragma unroll
            for (int kc = 0; kc < 2; ++kc) {
                union { short s[8]; short8 v; } u;
                __hip_bfloat16* h = (__hip_bfloat16*)u.s;
                h[0] = __float2bfloat16(sacc[mg][2 * kc][0]);
                h[1] = __float2bfloat16(sacc[mg][2 * kc][1]);
                h[2] = __float2bfloat16(sacc[mg][2 * kc][2]);
                h[3] = __float2bfloat16(sacc[mg][2 * kc][3]);
                h[4] = __float2bfloat16(sacc[mg][2 * kc + 1][0]);
                h[5] = __float2bfloat16(sacc[mg][2 * kc + 1][1]);
                h[6] = __float2bfloat16(sacc[mg][2 * kc + 1][2]);
                h[7] = __float2bfloat16(sacc[mg][2 * kc + 1][3]);
                ap[mg][kc] = u.v;
            }
#pragma unroll
            for (int nt = 0; nt < 8; ++nt)
#pragma unroll
                for (int r = 0; r < 4; ++r) o_acc[mg][nt][r] *= alpha;
        }

        // O^T += V P^T   (A = V rows d, B = in-register P)
#pragma unroll
        for (int kc = 0; kc < 2; ++kc)
#pragma unroll
            for (int nt = 0; nt < 8; ++nt) {
                short8 av = *(const short8*)((const char*)&sV[kc][0][0] + (nt * 16 + l16) * 64 + swzqV);
                o_acc[0][nt] = __builtin_amdgcn_mfma_f32_16x16x32_bf16(av, ap[0][kc], o_acc[0][nt], 0, 0, 0);
                o_acc[1][nt] = __builtin_amdgcn_mfma_f32_16x16x32_bf16(av, ap[1][kc], o_acc[1][nt], 0, 0, 0);
            }
    }

    // write O in place over this block's own Q region (O^T regs: q lane-local)
#pragma unroll
    for (int mg = 0; mg < 2; ++mg) {
        int s = q0 + wave * 32 + mg * 16 + l16;
        size_t base = (size_t)(s * 4 + b) * 2048 + nh * 128;
        float inv = 1.0f / l_i[mg];
#pragma unroll
        for (int nt = 0; nt < 8; ++nt) {
            union { short h[4]; uint2 v; } u;
            __hip_bfloat16* hh = (__hip_bfloat16*)u.h;
            hh[0] = __float2bfloat16(o_acc[mg][nt][0] * inv);
            hh[1] = __float2bfloat16(o_acc[mg][nt][1] * inv);
            hh[2] = __float2bfloat16(o_acc[mg][nt][2] * inv);
            hh[3] = __float2bfloat16(o_acc[mg][nt][3] * inv);
            *(uint2*)(Qio + base + nt * 16 + quad * 4) = u.v;
        }
    }
}

// ---------------------------------------------------------------- launch
extern "C" void kernel_launch(void* const* d_in, const int* in_sizes, int n_in,
                              void* d_out, int out_size, void* d_ws, size_t ws_size,
                              hipStream_t stream) {
    const float* x  = (const float*)d_in[0];
    const float* wq = (const float*)d_in[1];
    const float* bq = (const float*)d_in[2];
    const float* wk = (const float*)d_in[3];
    const float* bk = (const float*)d_in[4];
    const float* wv = (const float*)d_in[5];
    const float* bv = (const float*)d_in[6];
    const float* wd = (const float*)d_in[7];
    const float* bd = (const float*)d_in[8];
    // d_in[9] = start_pos: unused (reference recomputes t=arange(seq))

    const size_t TH = (size_t)8192 * 2048;  // 16.7M elems
    const size_t HH = (size_t)2048 * 2048;  // 4M elems
    dim3 gg(64, 16);

    if (ws_size >= (136ull << 20)) {
        // spacious: pre-convert to bf16, all GEMMs fully async (m97-style)
        __hip_bfloat16* xb  = (__hip_bfloat16*)d_ws;
        __hip_bfloat16* Qb  = xb + TH;
        __hip_bfloat16* Kb  = Qb + TH;
        __hip_bfloat16* Vtb = Kb + TH;
        __hip_bfloat16* wb  = Vtb + TH;  // reused per GEMM

        cvt_bf16<<<(int)(TH / 1024), 256, 0, stream>>>(x, xb, (int)TH);
        cvt_bf16<<<(int)(HH / 1024), 256, 0, stream>>>(wq, wb, (int)HH);
        gemm_k<1, 1, 1><<<gg, 256, 0, stream>>>(xb, wb, bq, Qb, 8192, 2048, 2048);
        cvt_bf16<<<(int)(HH / 1024), 256, 0, stream>>>(wk, wb, (int)HH);
        gemm_k<1, 1, 1><<<gg, 256, 0, stream>>>(xb, wb, bk, Kb, 8192, 2048, 2048);
        cvt_bf16<<<(int)(HH / 1024), 256, 0, stream>>>(wv, wb, (int)HH);
        gemm_k<1, 1, 2><<<gg, 256, 0, stream>>>(xb, wb, bv, Vtb, 8192, 2048, 2048);

        rope_kernel<<<32768, 256, 0, stream>>>(Qb, Kb);
        attn_kernel<<<dim3(64, 16), 256, 0, stream>>>(Qb, Kb, Vtb);

        cvt_bf16<<<(int)(HH / 1024), 256, 0, stream>>>(wd, wb, (int)HH);
        gemm_k<1, 1, 0><<<gg, 256, 0, stream>>>(Qb, wb, bd, d_out, 8192, 2048, 2048);
    } else {
        // tight (96 MiB total scratch): Q in ws; K,Vt inside d_out
        __hip_bfloat16* Qb = (__hip_bfloat16*)d_ws;
        __hip_bfloat16* Kb = (__hip_bfloat16*)d_out;
        __hip_bfloat16* Vt = (__hip_bfloat16*)d_out + TH;

        gemm_k<0, 0, 1><<<gg, 256, 0, stream>>>(x, wq, bq, Qb, 8192, 2048, 2048);
        gemm_k<0, 0, 1><<<gg, 256, 0, stream>>>(x, wk, bk, Kb, 8192, 2048, 2048);
        gemm_k<0, 0, 2><<<gg, 256, 0, stream>>>(x, wv, bv, Vt, 8192, 2048, 2048);

        rope_kernel<<<32768, 256, 0, stream>>>(Qb, Kb);
        attn_kernel<<<dim3(64, 16), 256, 0, stream>>>(Qb, Kb, Vt);

        // final projection: A (attn out) is bf16 -> async; B stays f32 sync-cvt
        gemm_k<1, 0, 0><<<gg, 256, 0, stream>>>(Qb, wd, bd, d_out, 8192, 2048, 2048);
    }
    (void)in_sizes; (void)n_in; (void)out_size; (void)ws_size;
}

// Round 2
// 699.032 us; speedup vs baseline: 1.0192x; 1.0192x over previous
//
#include <hip/hip_runtime.h>
#include <hip/hip_bf16.h>
#include <stdint.h>

typedef __attribute__((ext_vector_type(8))) short short8;
typedef __attribute__((ext_vector_type(4))) float floatx4;

#define AS1 __attribute__((address_space(1)))
#define AS3 __attribute__((address_space(3)))

// async global->LDS, 16B/lane. HW dest = wave-uniform base + lane*16, so every
// call site ensures its lane's dst == base + lane*16 (contiguous by lane).
__device__ __forceinline__ void async_copy16(const void* g, void* l) {
    __builtin_amdgcn_global_load_lds((const AS1 uint32_t*)(uintptr_t)g,
                                     (AS3 uint32_t*)(uintptr_t)l, 16, 0, 0);
}

// LDS swizzle: 64B rows of 4x16B chunks; logical chunk c of row r lives at
// phys chunk c ^ swz(r).  GEMM/sV use swz(r) = (r>>1)&3 (consecutive-row reads,
// 8-lane groups cover all 32 banks -> conflict-free, measured 0).
// attn sK uses swz(r) = (r>>1 & 1) | (r>>3 & 1)<<1: the sigma-permuted reads
// touch rows {B,B+1,B+2,B+3,B+8,B+9,B+10,B+11} per 8-lane group, and this swz
// is injective on (bit1,bit3) -> the 4 even(odd) rows get 4 distinct chunk
// slots -> full 32-bank coverage per group (the old swz aliased R and R+10).

// load 8 f32 -> 8 bf16 packed
__device__ __forceinline__ short8 cvt8(const float* p) {
    float4 a = *(const float4*)p;
    float4 b = *(const float4*)(p + 4);
    union { short s[8]; short8 v; } u;
    __hip_bfloat16* h = (__hip_bfloat16*)u.s;
    h[0] = __float2bfloat16(a.x); h[1] = __float2bfloat16(a.y);
    h[2] = __float2bfloat16(a.z); h[3] = __float2bfloat16(a.w);
    h[4] = __float2bfloat16(b.x); h[5] = __float2bfloat16(b.y);
    h[6] = __float2bfloat16(b.z); h[7] = __float2bfloat16(b.w);
    return u.v;
}

// ---------------------------------------------------------------- cvt f32->bf16
__global__ __launch_bounds__(256) void cvt_bf16(const float* __restrict__ s,
                                                __hip_bfloat16* __restrict__ d, int n) {
    int i = ((int)blockIdx.x * 256 + (int)threadIdx.x) * 4;
    if (i >= n) return;
    const float4 v = *(const float4*)(s + i);
    ushort4 pk;
    __hip_bfloat16* ph = (__hip_bfloat16*)&pk;
    ph[0] = __float2bfloat16(v.x); ph[1] = __float2bfloat16(v.y);
    ph[2] = __float2bfloat16(v.z); ph[3] = __float2bfloat16(v.w);
    *(ushort4*)(d + i) = pk;
}

// ---------------------------------------------------------------- GEMM
// C = A @ Bt^T + bias. 128x128 tile, BK=32, 4 waves 2x2.
// A_ASYNC: 1 -> A is bf16, staged via global_load_lds; 0 -> A f32, sync cvt.
// B_ASYNC: same for B. STORE_MODE: 0 f32; 1 bf16; 2 bf16 V-transpose
//   (row=t,col=hid) -> Vt[(b*16+nh)*128+d][s], s=t>>2,b=t&3,nh=col>>7,d=col&127.
template <int A_ASYNC, int B_ASYNC, int STORE_MODE>
__global__ __launch_bounds__(256, 2) void gemm_k(const void* __restrict__ Av,
                                                 const void* __restrict__ Bv,
                                                 const float* __restrict__ bias,
                                                 void* __restrict__ Cv,
                                                 int M, int N, int K) {
    __shared__ __align__(16) __hip_bfloat16 sA[128 * 32];
    __shared__ __align__(16) __hip_bfloat16 sB[128 * 32];
    const int tid  = threadIdx.x;
    const int wave = tid >> 6, lane = tid & 63;
    const int quad = lane >> 4, l16 = lane & 15;
    const int m0 = blockIdx.x * 128, n0 = blockIdx.y * 128;
    const int wm = (wave >> 1) * 64, wn = (wave & 1) * 64;
    const int lrow   = lane >> 2;
    const int srcoff = (((lane & 3) ^ ((lane >> 3) & 3)) * 16);  // swizzled chunk, bytes
    const int dstoff = (lane & 3) * 16;                          // phys chunk, bytes
    const int swzq   = (quad ^ ((l16 >> 1) & 3)) * 16;           // fragment chunk, bytes

    floatx4 acc[4][4];
#pragma unroll
    for (int i = 0; i < 4; i++)
#pragma unroll
        for (int j = 0; j < 4; j++) acc[i][j] = (floatx4)0.0f;

    for (int k0 = 0; k0 < K; k0 += 32) {
        short8 va[2], vb[2];
#pragma unroll
        for (int c = 0; c < 2; ++c) {  // pre-barrier global loads for sync operands
            int r = wave * 32 + c * 16 + lrow;
            if (!A_ASYNC) va[c] = cvt8((const float*)Av + (size_t)(m0 + r) * K + k0 + (lane & 3) * 8);
            if (!B_ASYNC) vb[c] = cvt8((const float*)Bv + (size_t)(n0 + r) * K + k0 + (lane & 3) * 8);
        }
        __syncthreads();  // prior iteration's fragment reads done
#pragma unroll
        for (int c = 0; c < 2; ++c) {
            int r = wave * 32 + c * 16 + lrow;
            if (A_ASYNC)
                async_copy16((const char*)((const __hip_bfloat16*)Av + (size_t)(m0 + r) * K + k0) + srcoff,
                             (char*)sA + r * 64 + dstoff);
            else
                *(short8*)((char*)sA + r * 64 + srcoff) = va[c];
            if (B_ASYNC)
                async_copy16((const char*)((const __hip_bfloat16*)Bv + (size_t)(n0 + r) * K + k0) + srcoff,
                             (char*)sB + r * 64 + dstoff);
            else
                *(short8*)((char*)sB + r * 64 + srcoff) = vb[c];
        }
        __syncthreads();  // drain staging (vmcnt/lgkm before barrier)

        short8 af[4], bf[4];
#pragma unroll
        for (int i = 0; i < 4; i++)
            af[i] = *(const short8*)((const char*)sA + (wm + i * 16 + l16) * 64 + swzq);
#pragma unroll
        for (int j = 0; j < 4; j++)
            bf[j] = *(const short8*)((const char*)sB + (wn + j * 16 + l16) * 64 + swzq);
#pragma unroll
        for (int i = 0; i < 4; i++)
#pragma unroll
            for (int j = 0; j < 4; j++)
                acc[i][j] = __builtin_amdgcn_mfma_f32_16x16x32_bf16(af[i], bf[j], acc[i][j], 0, 0, 0);
    }

#pragma unroll
    for (int i = 0; i < 4; i++) {
#pragma unroll
        for (int j = 0; j < 4; j++) {
            int col  = n0 + wn + j * 16 + l16;
            float bv = bias[col];
#pragma unroll
            for (int r = 0; r < 4; ++r) {
                int row = m0 + wm + i * 16 + quad * 4 + r;  // C-layout: row=quad*4+reg
                float v = acc[i][j][r] + bv;
                if (STORE_MODE == 0) {
                    ((float*)Cv)[(size_t)row * N + col] = v;
                } else if (STORE_MODE == 1) {
                    ((__hip_bfloat16*)Cv)[(size_t)row * N + col] = __float2bfloat16(v);
                } else {
                    int s = row >> 2, b = row & 3, nh = col >> 7, d = col & 127;
                    ((__hip_bfloat16*)Cv)[((size_t)(b * 16 + nh) * 128 + d) * 2048 + s] =
                        __float2bfloat16(v);
                }
            }
        }
    }
}

// ---------------------------------------------------------------- RoPE (in-place)
__global__ __launch_bounds__(256) void rope_kernel(__hip_bfloat16* __restrict__ Q,
                                                   __hip_bfloat16* __restrict__ K) {
    const int PER = 8192 * 16 * 32;
    int idx = (int)blockIdx.x * 256 + (int)threadIdx.x;
    __hip_bfloat16* base = (idx < PER) ? Q : K;
    int i  = (idx < PER) ? idx : idx - PER;
    int p  = i & 31;
    int nh = (i >> 5) & 15;
    int t  = i >> 9;
    int s  = t >> 2;
    float inv = __expf(-(float)(p & 15) * 0.5756462732485115f);  // ln(10000)/16
    float ang = (float)s * inv;
    float c = cosf(ang), sn = sinf(ang);
    size_t off = (size_t)t * 2048 + nh * 128 + 2 * p;
    float x0 = __bfloat162float(base[off]);
    float x1 = __bfloat162float(base[off + 1]);
    base[off]     = __float2bfloat16(x0 * c - x1 * sn);
    base[off + 1] = __float2bfloat16(x0 * sn + x1 * c);
}

// ---------------------------------------------------------------- flash attention
// Qio [t][2048] (roped; O overwrites in place), Km [t][2048], Vt [bh][128][2048].
// Block (bh, qt): 128 q-rows, 64 kv/iter; wave owns 32 q rows (2 m-groups).
//
// Swapped-operand scheme: S^T = mfma(K, Q) with PERMUTED K-fragment rows
//   sigma(nt, i) = 32*(nt>>1) + 8*(i>>2) + 4*(nt&1) + (i&3)
// so after softmax each lane (quad,l16) holds exactly P[q=l16][kv=quad*8+0..7]
// of each 32-kv chunk == the B-fragment of O^T = mfma(V, P). No sP LDS, no
// cross-lane P traffic, and softmax reduces are 2 shfl steps (cross-quad only).
// sO (16 KiB) transposes O per-wave for full-64B-sector stores AND caps LDS at
// 48 KiB -> 3 blocks/CU (round-1's 5 blocks/CU thrashed L2/L3: FETCH 82->224MB).
__global__ __launch_bounds__(256, 3) void attn_kernel(__hip_bfloat16* __restrict__ Qio,
                                                      const __hip_bfloat16* __restrict__ Km,
                                                      const __hip_bfloat16* __restrict__ Vt) {
    __shared__ __align__(16) __hip_bfloat16 sK[4][64][32];   // [d-chunk][kv][32d]
    __shared__ __align__(16) __hip_bfloat16 sV[2][128][32];  // [kv-chunk][d][32kv]
    __shared__ __align__(16) __hip_bfloat16 sO[4][16][128];  // per-wave O transpose
    const int tid  = threadIdx.x;
    const int wave = tid >> 6, lane = tid & 63;
    const int quad = lane >> 4, l16 = lane & 15;
    const int bh = blockIdx.x, b = bh >> 4, nh = bh & 15;
    const int qtl = 15 - (int)blockIdx.y;  // longest blocks first
    const int q0  = qtl * 128;
    const int lrow    = lane >> 2;
    const int dstoff  = (lane & 3) * 16;
    const int srcoffV = (((lane & 3) ^ ((lane >> 3) & 3)) * 16);  // sV: swz(r)=(r>>1)&3
    const int swzqV   = (quad ^ ((l16 >> 1) & 3)) * 16;
    const float scale = 0.08838834764831845f;  // 1/sqrt(128)

    // Q fragments (B-operand) in registers: rows wave*32+mg*16+l16, k = kk*32+quad*8+j
    short8 qf[2][4];
#pragma unroll
    for (int mg = 0; mg < 2; ++mg)
#pragma unroll
        for (int kk = 0; kk < 4; ++kk) {
            int qrow = wave * 32 + mg * 16 + l16;
            int t    = (q0 + qrow) * 4 + b;
            qf[mg][kk] = *(const short8*)(Qio + (size_t)t * 2048 + nh * 128 + kk * 32 + quad * 8);
        }

    float m_i[2], l_i[2];
#pragma unroll
    for (int mg = 0; mg < 2; ++mg) { m_i[mg] = -1e30f; l_i[mg] = 0.f; }
    floatx4 o_acc[2][8];  // O^T: d = nt*16 + quad*4 + r, q = l16 (per mg)
#pragma unroll
    for (int mg = 0; mg < 2; ++mg)
#pragma unroll
        for (int n = 0; n < 8; ++n) o_acc[mg][n] = (floatx4)0.0f;

    const int nk = 2 * qtl + 2;
    for (int kt = 0; kt < nk; ++kt) {
        __syncthreads();  // prior iter's sK/sV reads done
        {
#pragma unroll
            for (int c = 0; c < 4; ++c) {
                int krow = c * 16 + lrow;
                int swzK = ((krow >> 1) & 1) | (((krow >> 3) & 1) << 1);  // injective on (b1,b3)
                int srcK = ((lane & 3) ^ swzK) * 16;
                int t    = (kt * 64 + krow) * 4 + b;
                async_copy16((const char*)(Km + (size_t)t * 2048 + nh * 128 + wave * 32) + srcK,
                             (char*)&sK[wave][0][0] + krow * 64 + dstoff);
            }
            const int kc = wave >> 1, dh = (wave & 1) * 64;
#pragma unroll
            for (int c = 0; c < 4; ++c) {
                int d = dh + c * 16 + lrow;
                async_copy16((const char*)(Vt + ((size_t)bh * 128 + d) * 2048 + kt * 64 + kc * 32) + srcoffV,
                             (char*)&sV[kc][0][0] + d * 64 + dstoff);
            }
        }
        __syncthreads();  // drain staging

        // S^T = K Q^T (A = permuted K rows, B = Q). D[kv'][q] per 16x16 tile.
        floatx4 sacc[2][4];
#pragma unroll
        for (int mg = 0; mg < 2; ++mg)
#pragma unroll
            for (int n = 0; n < 4; ++n) sacc[mg][n] = (floatx4)0.0f;
#pragma unroll
        for (int nt = 0; nt < 4; ++nt) {
            int R    = (nt >> 1) * 32 + (l16 >> 2) * 8 + (nt & 1) * 4 + (l16 & 3);  // sigma row
            int swzK = ((R >> 1) & 1) | (((R >> 3) & 1) << 1);
            int off  = R * 64 + (quad ^ swzK) * 16;
#pragma unroll
            for (int kk = 0; kk < 4; ++kk) {
                short8 ak = *(const short8*)((const char*)&sK[kk][0][0] + off);
                sacc[0][nt] = __builtin_amdgcn_mfma_f32_16x16x32_bf16(ak, qf[0][kk], sacc[0][nt], 0, 0, 0);
                sacc[1][nt] = __builtin_amdgcn_mfma_f32_16x16x32_bf16(ak, qf[1][kk], sacc[1][nt], 0, 0, 0);
            }
        }

        // online softmax, fully in-register; P packed straight into B-fragments
        short8 ap[2][2];  // [mg][kv 32-chunk]
#pragma unroll
        for (int mg = 0; mg < 2; ++mg) {
            const int q     = q0 + wave * 32 + mg * 16 + l16;
            const bool dmask = (kt * 64 + 63) > (q0 + wave * 32 + mg * 16);
            float mx = -1e30f;
#pragma unroll
            for (int nt = 0; nt < 4; ++nt) {
                int kvb = kt * 64 + (nt >> 1) * 32 + quad * 8 + (nt & 1) * 4;  // sigma(nt, quad*4+r)
#pragma unroll
                for (int r = 0; r < 4; ++r) {
                    float v = sacc[mg][nt][r] * scale;
                    if (dmask && (kvb + r > q)) v = -1e30f;
                    sacc[mg][nt][r] = v;
                    mx = fmaxf(mx, v);
                }
            }
            mx = fmaxf(mx, __shfl_xor(mx, 16, 64));  // cross-quad only: q is lane-local
            mx = fmaxf(mx, __shfl_xor(mx, 32, 64));
            float mnew  = fmaxf(m_i[mg], mx);
            float alpha = __expf(m_i[mg] - mnew);
            m_i[mg] = mnew;
            float rs = 0.f;
#pragma unroll
            for (int nt = 0; nt < 4; ++nt)
#pragma unroll
                for (int r = 0; r < 4; ++r) {
                    float e = __expf(sacc[mg][nt][r] - mnew);
                    sacc[mg][nt][r] = e;
                    rs += e;
                }
            rs += __shfl_xor(rs, 16, 64);
            rs += __shfl_xor(rs, 32, 64);
            l_i[mg] = l_i[mg] * alpha + rs;
            // pack B-fragment: k-slot j<4 -> nt=2kc, j>=4 -> nt=2kc+1 (kv = quad*8+j)
#pragma unroll
            for (int kc = 0; kc < 2; ++kc) {
                union { short s[8]; short8 v; } u;
                __hip_bfloat16* h = (__hip_bfloat16*)u.s;
                h[0] = __float2bfloat16(sacc[mg][2 * kc][0]);
                h[1] = __float2bfloat16(sacc[mg][2 * kc][1]);
                h[2] = __float2bfloat16(sacc[mg][2 * kc][2]);
                h[3] = __float2bfloat16(sacc[mg][2 * kc][3]);
                h[4] = __float2bfloat16(sacc[mg][2 * kc + 1][0]);
                h[5] = __float2bfloat16(sacc[mg][2 * kc + 1][1]);
                h[6] = __float2bfloat16(sacc[mg][2 * kc + 1][2]);
                h[7] = __float2bfloat16(sacc[mg][2 * kc + 1][3]);
                ap[mg][kc] = u.v;
            }
#pragma unroll
            for (int nt = 0; nt < 8; ++nt)
#pragma unroll
                for (int r = 0; r < 4; ++r) o_acc[mg][nt][r] *= alpha;
        }

        // O^T += V P^T   (A = V rows d, B = in-register P)
#pragma unroll
        for (int kc = 0; kc < 2; ++kc)
#pragma unroll
            for (int nt = 0; nt < 8; ++nt) {
                short8 av = *(const short8*)((const char*)&sV[kc][0][0] + (nt * 16 + l16) * 64 + swzqV);
                o_acc[0][nt] = __builtin_amdgcn_mfma_f32_16x16x32_bf16(av, ap[0][kc], o_acc[0][nt], 0, 0, 0);
                o_acc[1][nt] = __builtin_amdgcn_mfma_f32_16x16x32_bf16(av, ap[1][kc], o_acc[1][nt], 0, 0, 0);
            }
    }

    // epilogue: per-wave transpose via sO, then full-64B-sector global stores.
    // write: row q=l16, logical 16B chunk c16 = 2nt+(quad>>1), half = quad&1,
    //        phys chunk pc = c16 ^ ((q>>1)&3)  (2-way max on banks = free)
    // read : lane -> row lane>>2, chunk (lane&3)+4cc -> 4 lanes x 16B = 64B/row
#pragma unroll
    for (int mg = 0; mg < 2; ++mg) {
        float inv = 1.0f / l_i[mg];
#pragma unroll
        for (int nt = 0; nt < 8; ++nt) {
            union { short h[4]; uint2 v; } u;
            __hip_bfloat16* hh = (__hip_bfloat16*)u.h;
            hh[0] = __float2bfloat16(o_acc[mg][nt][0] * inv);
            hh[1] = __float2bfloat16(o_acc[mg][nt][1] * inv);
            hh[2] = __float2bfloat16(o_acc[mg][nt][2] * inv);
            hh[3] = __float2bfloat16(o_acc[mg][nt][3] * inv);
            int pc = (2 * nt + (quad >> 1)) ^ ((l16 >> 1) & 3);
            *(uint2*)((char*)&sO[wave][0][0] + l16 * 256 + pc * 16 + (quad & 1) * 8) = u.v;
        }
        // wave-local transpose: LDS ops from one wave complete in order; the
        // compiler inserts lgkmcnt for the write->read dependency on sO.
#pragma unroll
        for (int cc = 0; cc < 4; ++cc) {
            int qr  = lane >> 2;            // 0..15
            int c16 = (lane & 3) + cc * 4;  // logical 16B chunk
            int pc  = c16 ^ ((qr >> 1) & 3);
            short8 ov = *(const short8*)((const char*)&sO[wave][0][0] + qr * 256 + pc * 16);
            int s = q0 + wave * 32 + mg * 16 + qr;
            *(short8*)(Qio + (size_t)(s * 4 + b) * 2048 + nh * 128 + c16 * 8) = ov;
        }
    }
}

// ---------------------------------------------------------------- launch
extern "C" void kernel_launch(void* const* d_in, const int* in_sizes, int n_in,
                              void* d_out, int out_size, void* d_ws, size_t ws_size,
                              hipStream_t stream) {
    const float* x  = (const float*)d_in[0];
    const float* wq = (const float*)d_in[1];
    const float* bq = (const float*)d_in[2];
    const float* wk = (const float*)d_in[3];
    const float* bk = (const float*)d_in[4];
    const float* wv = (const float*)d_in[5];
    const float* bv = (const float*)d_in[6];
    const float* wd = (const float*)d_in[7];
    const float* bd = (const float*)d_in[8];
    // d_in[9] = start_pos: unused (reference recomputes t=arange(seq))

    const size_t TH = (size_t)8192 * 2048;  // 16.7M elems
    const size_t HH = (size_t)2048 * 2048;  // 4M elems
    dim3 gg(64, 16);

    if (ws_size >= (136ull << 20)) {
        // spacious: pre-convert to bf16, all GEMMs fully async (m97-style)
        __hip_bfloat16* xb  = (__hip_bfloat16*)d_ws;
        __hip_bfloat16* Qb  = xb + TH;
        __hip_bfloat16* Kb  = Qb + TH;
        __hip_bfloat16* Vtb = Kb + TH;
        __hip_bfloat16* wb  = Vtb + TH;  // reused per GEMM

        cvt_bf16<<<(int)(TH / 1024), 256, 0, stream>>>(x, xb, (int)TH);
        cvt_bf16<<<(int)(HH / 1024), 256, 0, stream>>>(wq, wb, (int)HH);
        gemm_k<1, 1, 1><<<gg, 256, 0, stream>>>(xb, wb, bq, Qb, 8192, 2048, 2048);
        cvt_bf16<<<(int)(HH / 1024), 256, 0, stream>>>(wk, wb, (int)HH);
        gemm_k<1, 1, 1><<<gg, 256, 0, stream>>>(xb, wb, bk, Kb, 8192, 2048, 2048);
        cvt_bf16<<<(int)(HH / 1024), 256, 0, stream>>>(wv, wb, (int)HH);
        gemm_k<1, 1, 2><<<gg, 256, 0, stream>>>(xb, wb, bv, Vtb, 8192, 2048, 2048);

        rope_kernel<<<32768, 256, 0, stream>>>(Qb, Kb);
        attn_kernel<<<dim3(64, 16), 256, 0, stream>>>(Qb, Kb, Vtb);

        cvt_bf16<<<(int)(HH / 1024), 256, 0, stream>>>(wd, wb, (int)HH);
        gemm_k<1, 1, 0><<<gg, 256, 0, stream>>>(Qb, wb, bd, d_out, 8192, 2048, 2048);
    } else {
        // tight (96 MiB total scratch): Q in ws; K,Vt inside d_out
        __hip_bfloat16* Qb = (__hip_bfloat16*)d_ws;
        __hip_bfloat16* Kb = (__hip_bfloat16*)d_out;
        __hip_bfloat16* Vt = (__hip_bfloat16*)d_out + TH;

        gemm_k<0, 0, 1><<<gg, 256, 0, stream>>>(x, wq, bq, Qb, 8192, 2048, 2048);
        gemm_k<0, 0, 1><<<gg, 256, 0, stream>>>(x, wk, bk, Kb, 8192, 2048, 2048);
        gemm_k<0, 0, 2><<<gg, 256, 0, stream>>>(x, wv, bv, Vt, 8192, 2048, 2048);

        rope_kernel<<<32768, 256, 0, stream>>>(Qb, Kb);
        attn_kernel<<<dim3(64, 16), 256, 0, stream>>>(Qb, Kb, Vt);

        // final projection: A (attn out) is bf16 -> async; B stays f32 sync-cvt
        gemm_k<1, 0, 0><<<gg, 256, 0, stream>>>(Qb, wd, bd, d_out, 8192, 2048, 2048);
    }
    (void)in_sizes; (void)n_in; (void)out_size; (void)ws_size;
}

// Round 4
// 620.723 us; speedup vs baseline: 1.1478x; 1.1262x over previous
//
#include <hip/hip_runtime.h>
#include <hip/hip_bf16.h>
#include <stdint.h>

typedef __attribute__((ext_vector_type(8))) short short8;
typedef __attribute__((ext_vector_type(4))) float floatx4;

#define AS1 __attribute__((address_space(1)))
#define AS3 __attribute__((address_space(3)))

// async global->LDS, 16B/lane. HW dest = wave-uniform base + lane*16, so every
// call site ensures its lane's dst == base + lane*16 (contiguous by lane).
__device__ __forceinline__ void async_copy16(const void* g, void* l) {
    __builtin_amdgcn_global_load_lds((const AS1 uint32_t*)(uintptr_t)g,
                                     (AS3 uint32_t*)(uintptr_t)l, 16, 0, 0);
}

// LDS swizzle: 64B rows of 4x16B chunks; logical chunk c of row r lives at
// phys chunk c ^ swz(r).  GEMM/sV use swz(r) = (r>>1)&3 (consecutive-row reads,
// 8-lane groups cover all 32 banks -> conflict-free, measured 0).
// attn sK uses swz(r) = (r>>1 & 1) | (r>>3 & 1)<<1: the sigma-permuted reads
// touch rows {B,B+1,B+2,B+3,B+8,B+9,B+10,B+11} per 8-lane group; injective on
// (bit1,bit3) -> full 32-bank coverage per group (verified r2: conflicts 4.4M->1.2M,
// remainder is the 2-way sO epilogue, free per m136).

// load 8 f32 -> 8 bf16 packed
__device__ __forceinline__ short8 cvt8(const float* p) {
    float4 a = *(const float4*)p;
    float4 b = *(const float4*)(p + 4);
    union { short s[8]; short8 v; } u;
    __hip_bfloat16* h = (__hip_bfloat16*)u.s;
    h[0] = __float2bfloat16(a.x); h[1] = __float2bfloat16(a.y);
    h[2] = __float2bfloat16(a.z); h[3] = __float2bfloat16(a.w);
    h[4] = __float2bfloat16(b.x); h[5] = __float2bfloat16(b.y);
    h[6] = __float2bfloat16(b.z); h[7] = __float2bfloat16(b.w);
    return u.v;
}

// ---------------------------------------------------------------- cvt f32->bf16
__global__ __launch_bounds__(256) void cvt_bf16(const float* __restrict__ s,
                                                __hip_bfloat16* __restrict__ d, int n) {
    int i = ((int)blockIdx.x * 256 + (int)threadIdx.x) * 4;
    if (i >= n) return;
    const float4 v = *(const float4*)(s + i);
    ushort4 pk;
    __hip_bfloat16* ph = (__hip_bfloat16*)&pk;
    ph[0] = __float2bfloat16(v.x); ph[1] = __float2bfloat16(v.y);
    ph[2] = __float2bfloat16(v.z); ph[3] = __float2bfloat16(v.w);
    *(ushort4*)(d + i) = pk;
}

// ---------------------------------------------------------------- GEMM
// C = A @ Bt^T + bias. 128x128 tile, BK=32, 4 waves 2x2.
// A_ASYNC: 1 -> A is bf16, staged via global_load_lds; 0 -> A f32, sync cvt.
// B_ASYNC: same for B. STORE_MODE: 0 f32; 1 bf16; 2 bf16 V-transpose
//   (row=t,col=hid) -> Vt[(b*16+nh)*128+d][s], s=t>>2,b=t&3,nh=col>>7,d=col&127.
template <int A_ASYNC, int B_ASYNC, int STORE_MODE>
__global__ __launch_bounds__(256, 2) void gemm_k(const void* __restrict__ Av,
                                                 const void* __restrict__ Bv,
                                                 const float* __restrict__ bias,
                                                 void* __restrict__ Cv,
                                                 int M, int N, int K) {
    __shared__ __align__(16) __hip_bfloat16 sA[128 * 32];
    __shared__ __align__(16) __hip_bfloat16 sB[128 * 32];
    const int tid  = threadIdx.x;
    const int wave = tid >> 6, lane = tid & 63;
    const int quad = lane >> 4, l16 = lane & 15;
    const int m0 = blockIdx.x * 128, n0 = blockIdx.y * 128;
    const int wm = (wave >> 1) * 64, wn = (wave & 1) * 64;
    const int lrow   = lane >> 2;
    const int srcoff = (((lane & 3) ^ ((lane >> 3) & 3)) * 16);  // swizzled chunk, bytes
    const int dstoff = (lane & 3) * 16;                          // phys chunk, bytes
    const int swzq   = (quad ^ ((l16 >> 1) & 3)) * 16;           // fragment chunk, bytes

    floatx4 acc[4][4];
#pragma unroll
    for (int i = 0; i < 4; i++)
#pragma unroll
        for (int j = 0; j < 4; j++) acc[i][j] = (floatx4)0.0f;

    for (int k0 = 0; k0 < K; k0 += 32) {
        short8 va[2], vb[2];
#pragma unroll
        for (int c = 0; c < 2; ++c) {  // pre-barrier global loads for sync operands
            int r = wave * 32 + c * 16 + lrow;
            if (!A_ASYNC) va[c] = cvt8((const float*)Av + (size_t)(m0 + r) * K + k0 + (lane & 3) * 8);
            if (!B_ASYNC) vb[c] = cvt8((const float*)Bv + (size_t)(n0 + r) * K + k0 + (lane & 3) * 8);
        }
        __syncthreads();  // prior iteration's fragment reads done
#pragma unroll
        for (int c = 0; c < 2; ++c) {
            int r = wave * 32 + c * 16 + lrow;
            if (A_ASYNC)
                async_copy16((const char*)((const __hip_bfloat16*)Av + (size_t)(m0 + r) * K + k0) + srcoff,
                             (char*)sA + r * 64 + dstoff);
            else
                *(short8*)((char*)sA + r * 64 + srcoff) = va[c];
            if (B_ASYNC)
                async_copy16((const char*)((const __hip_bfloat16*)Bv + (size_t)(n0 + r) * K + k0) + srcoff,
                             (char*)sB + r * 64 + dstoff);
            else
                *(short8*)((char*)sB + r * 64 + srcoff) = vb[c];
        }
        __syncthreads();  // drain staging (vmcnt/lgkm before barrier)

        short8 af[4], bf[4];
#pragma unroll
        for (int i = 0; i < 4; i++)
            af[i] = *(const short8*)((const char*)sA + (wm + i * 16 + l16) * 64 + swzq);
#pragma unroll
        for (int j = 0; j < 4; j++)
            bf[j] = *(const short8*)((const char*)sB + (wn + j * 16 + l16) * 64 + swzq);
#pragma unroll
        for (int i = 0; i < 4; i++)
#pragma unroll
            for (int j = 0; j < 4; j++)
                acc[i][j] = __builtin_amdgcn_mfma_f32_16x16x32_bf16(af[i], bf[j], acc[i][j], 0, 0, 0);
    }

#pragma unroll
    for (int i = 0; i < 4; i++) {
#pragma unroll
        for (int j = 0; j < 4; j++) {
            int col  = n0 + wn + j * 16 + l16;
            float bv = bias[col];
#pragma unroll
            for (int r = 0; r < 4; ++r) {
                int row = m0 + wm + i * 16 + quad * 4 + r;  // C-layout: row=quad*4+reg
                float v = acc[i][j][r] + bv;
                if (STORE_MODE == 0) {
                    ((float*)Cv)[(size_t)row * N + col] = v;
                } else if (STORE_MODE == 1) {
                    ((__hip_bfloat16*)Cv)[(size_t)row * N + col] = __float2bfloat16(v);
                } else {
                    int s = row >> 2, b = row & 3, nh = col >> 7, d = col & 127;
                    ((__hip_bfloat16*)Cv)[((size_t)(b * 16 + nh) * 128 + d) * 2048 + s] =
                        __float2bfloat16(v);
                }
            }
        }
    }
}

// ---------------------------------------------------------------- RoPE (in-place)
__global__ __launch_bounds__(256) void rope_kernel(__hip_bfloat16* __restrict__ Q,
                                                   __hip_bfloat16* __restrict__ K) {
    const int PER = 8192 * 16 * 32;
    int idx = (int)blockIdx.x * 256 + (int)threadIdx.x;
    __hip_bfloat16* base = (idx < PER) ? Q : K;
    int i  = (idx < PER) ? idx : idx - PER;
    int p  = i & 31;
    int nh = (i >> 5) & 15;
    int t  = i >> 9;
    int s  = t >> 2;
    float inv = __expf(-(float)(p & 15) * 0.5756462732485115f);  // ln(10000)/16
    float ang = (float)s * inv;
    float c = cosf(ang), sn = sinf(ang);
    size_t off = (size_t)t * 2048 + nh * 128 + 2 * p;
    float x0 = __bfloat162float(base[off]);
    float x1 = __bfloat162float(base[off + 1]);
    base[off]     = __float2bfloat16(x0 * c - x1 * sn);
    base[off + 1] = __float2bfloat16(x0 * sn + x1 * c);
}

// ---------------------------------------------------------------- flash attention
// Qio [t][2048] (roped; O overwrites in place), Km [t][2048], Vt [bh][128][2048].
// Block (bh, qt): 128 q-rows, 64 kv/iter; wave owns 32 q rows (2 m-groups).
//
// Swapped-operand scheme: S^T = mfma(K, Q) with PERMUTED K-fragment rows
//   sigma(nt, i) = 32*(nt>>1) + 8*(i>>2) + 4*(nt&1) + (i&3)
// so after softmax each lane (quad,l16) holds exactly P[q=l16][kv=quad*8+0..7]
// of each 32-kv chunk == the B-fragment of O^T = mfma(V, P). No sP LDS.
//
// T3+T4 pipeline: double-buffered sK/sV, counted vmcnt across raw s_barriers --
// stage(kt+1) is issued before compute(kt) and its 8 loads stay in flight
// through both barriers; only the OLDER 8 (stage kt) are waited on (vmcnt(8)).
// Never vmcnt(0) in the main loop => r2's per-iter latency drain (Mfma 17% /
// VALU 31% / HBM 13%, all idle) hides under compute.
__global__ __launch_bounds__(256, 2) void attn_kernel(__hip_bfloat16* __restrict__ Qio,
                                                      const __hip_bfloat16* __restrict__ Km,
                                                      const __hip_bfloat16* __restrict__ Vt) {
    // arena: buffer p at [p*32768, p*32768+32768): sK[4][64][32] then sV[2][128][32].
    // epilogue sO[4][16][128] aliases buffer 0 (safe: final-iter vmcnt(0) + barrier
    // precede it, and each wave's sO region is wave-local).
    __shared__ __align__(16) char smem[65536];
    const int tid  = threadIdx.x;
    const int wave = tid >> 6, lane = tid & 63;
    const int quad = lane >> 4, l16 = lane & 15;
    const int bh = blockIdx.x, b = bh >> 4, nh = bh & 15;
    const int qtl = 15 - (int)blockIdx.y;  // longest blocks first
    const int q0  = qtl * 128;
    const int lrow    = lane >> 2;
    const int dstoff  = (lane & 3) * 16;
    const int srcoffV = (((lane & 3) ^ ((lane >> 3) & 3)) * 16);  // sV: swz(r)=(r>>1)&3
    const int swzqV   = (quad ^ ((l16 >> 1) & 3)) * 16;
    const float scale = 0.08838834764831845f;  // 1/sqrt(128)

    // one stage = 8 async copies per wave (4 K + 4 V) into buffer p
    auto stage = [&](int kt, int p) {
        char* sKb = smem + p * 32768;
        char* sVb = sKb + 16384;
#pragma unroll
        for (int c = 0; c < 4; ++c) {
            int krow = c * 16 + lrow;
            int swzK = ((krow >> 1) & 1) | (((krow >> 3) & 1) << 1);  // injective on (b1,b3)
            int srcK = ((lane & 3) ^ swzK) * 16;
            int t    = (kt * 64 + krow) * 4 + b;
            async_copy16((const char*)(Km + (size_t)t * 2048 + nh * 128 + wave * 32) + srcK,
                         sKb + wave * 4096 + krow * 64 + dstoff);
        }
        const int kc = wave >> 1, dh = (wave & 1) * 64;
#pragma unroll
        for (int c = 0; c < 4; ++c) {
            int d = dh + c * 16 + lrow;
            async_copy16((const char*)(Vt + ((size_t)bh * 128 + d) * 2048 + kt * 64 + kc * 32) + srcoffV,
                         sVb + kc * 8192 + d * 64 + dstoff);
        }
    };

    // Q fragments (B-operand) in registers: rows wave*32+mg*16+l16, k = kk*32+quad*8+j
    short8 qf[2][4];
#pragma unroll
    for (int mg = 0; mg < 2; ++mg)
#pragma unroll
        for (int kk = 0; kk < 4; ++kk) {
            int qrow = wave * 32 + mg * 16 + l16;
            int t    = (q0 + qrow) * 4 + b;
            qf[mg][kk] = *(const short8*)(Qio + (size_t)t * 2048 + nh * 128 + kk * 32 + quad * 8);
        }

    float m_i[2], l_i[2];
#pragma unroll
    for (int mg = 0; mg < 2; ++mg) { m_i[mg] = -1e30f; l_i[mg] = 0.f; }
    floatx4 o_acc[2][8];  // O^T: d = nt*16 + quad*4 + r, q = l16 (per mg)
#pragma unroll
    for (int mg = 0; mg < 2; ++mg)
#pragma unroll
        for (int n = 0; n < 8; ++n) o_acc[mg][n] = (floatx4)0.0f;

    const int nk = 2 * qtl + 2;

    // prologue: stage tile 0, then full drain (__syncthreads emits
    // vmcnt(0)+lgkmcnt(0) before s_barrier) so the loop enters with a clean
    // vmcnt model.
    stage(0, 0);
    __syncthreads();

    for (int kt = 0; kt < nk; ++kt) {
        const int cur = kt & 1;
        if (kt + 1 < nk) {
            stage(kt + 1, cur ^ 1);  // 8 new loads; stays in flight across barriers
            asm volatile("s_waitcnt vmcnt(8)" ::: "memory");  // older 8 = stage(kt) done
        } else {
            asm volatile("s_waitcnt vmcnt(0)" ::: "memory");  // last tile: drain
        }
        __builtin_amdgcn_s_barrier();          // all waves' stage(kt) complete
        __builtin_amdgcn_sched_barrier(0);     // rule #18: pin ds_reads below barrier

        const char* sKb = smem + cur * 32768;
        const char* sVb = sKb + 16384;

        // S^T = K Q^T (A = permuted K rows, B = Q). D[kv'][q] per 16x16 tile.
        floatx4 sacc[2][4];
#pragma unroll
        for (int mg = 0; mg < 2; ++mg)
#pragma unroll
            for (int n = 0; n < 4; ++n) sacc[mg][n] = (floatx4)0.0f;
#pragma unroll
        for (int nt = 0; nt < 4; ++nt) {
            int R    = (nt >> 1) * 32 + (l16 >> 2) * 8 + (nt & 1) * 4 + (l16 & 3);  // sigma row
            int swzK = ((R >> 1) & 1) | (((R >> 3) & 1) << 1);
            int off  = R * 64 + (quad ^ swzK) * 16;
#pragma unroll
            for (int kk = 0; kk < 4; ++kk) {
                short8 ak = *(const short8*)(sKb + kk * 4096 + off);
                sacc[0][nt] = __builtin_amdgcn_mfma_f32_16x16x32_bf16(ak, qf[0][kk], sacc[0][nt], 0, 0, 0);
                sacc[1][nt] = __builtin_amdgcn_mfma_f32_16x16x32_bf16(ak, qf[1][kk], sacc[1][nt], 0, 0, 0);
            }
        }

        // online softmax, fully in-register; P packed straight into B-fragments
        short8 ap[2][2];  // [mg][kv 32-chunk]
#pragma unroll
        for (int mg = 0; mg < 2; ++mg) {
            const int q     = q0 + wave * 32 + mg * 16 + l16;
            const bool dmask = (kt * 64 + 63) > (q0 + wave * 32 + mg * 16);
            float mx = -1e30f;
#pragma unroll
            for (int nt = 0; nt < 4; ++nt) {
                int kvb = kt * 64 + (nt >> 1) * 32 + quad * 8 + (nt & 1) * 4;  // sigma(nt, quad*4+r)
#pragma unroll
                for (int r = 0; r < 4; ++r) {
                    float v = sacc[mg][nt][r] * scale;
                    if (dmask && (kvb + r > q)) v = -1e30f;
                    sacc[mg][nt][r] = v;
                    mx = fmaxf(mx, v);
                }
            }
            mx = fmaxf(mx, __shfl_xor(mx, 16, 64));  // cross-quad only: q is lane-local
            mx = fmaxf(mx, __shfl_xor(mx, 32, 64));
            float mnew  = fmaxf(m_i[mg], mx);
            float alpha = __expf(m_i[mg] - mnew);
            m_i[mg] = mnew;
            float rs = 0.f;
#pragma unroll
            for (int nt = 0; nt < 4; ++nt)
#pragma unroll
                for (int r = 0; r < 4; ++r) {
                    float e = __expf(sacc[mg][nt][r] - mnew);
                    sacc[mg][nt][r] = e;
                    rs += e;
                }
            rs += __shfl_xor(rs, 16, 64);
            rs += __shfl_xor(rs, 32, 64);
            l_i[mg] = l_i[mg] * alpha + rs;
            // pack B-fragment: k-slot j<4 -> nt=2kc, j>=4 -> nt=2kc+1 (kv = quad*8+j)
#pragma unroll
            for (int kc = 0; kc < 2; ++kc) {
                union { short s[8]; short8 v; } u;
                __hip_bfloat16* h = (__hip_bfloat16*)u.s;
                h[0] = __float2bfloat16(sacc[mg][2 * kc][0]);
                h[1] = __float2bfloat16(sacc[mg][2 * kc][1]);
                h[2] = __float2bfloat16(sacc[mg][2 * kc][2]);
                h[3] = __float2bfloat16(sacc[mg][2 * kc][3]);
                h[4] = __float2bfloat16(sacc[mg][2 * kc + 1][0]);
                h[5] = __float2bfloat16(sacc[mg][2 * kc + 1][1]);
                h[6] = __float2bfloat16(sacc[mg][2 * kc + 1][2]);
                h[7] = __float2bfloat16(sacc[mg][2 * kc + 1][3]);
                ap[mg][kc] = u.v;
            }
#pragma unroll
            for (int nt = 0; nt < 8; ++nt)
#pragma unroll
                for (int r = 0; r < 4; ++r) o_acc[mg][nt][r] *= alpha;
        }

        // O^T += V P^T   (A = V rows d, B = in-register P)
#pragma unroll
        for (int kc = 0; kc < 2; ++kc)
#pragma unroll
            for (int nt = 0; nt < 8; ++nt) {
                short8 av = *(const short8*)(sVb + kc * 8192 + (nt * 16 + l16) * 64 + swzqV);
                o_acc[0][nt] = __builtin_amdgcn_mfma_f32_16x16x32_bf16(av, ap[0][kc], o_acc[0][nt], 0, 0, 0);
                o_acc[1][nt] = __builtin_amdgcn_mfma_f32_16x16x32_bf16(av, ap[1][kc], o_acc[1][nt], 0, 0, 0);
            }

        asm volatile("s_waitcnt lgkmcnt(0)" ::: "memory");  // this wave's LDS reads done
        __builtin_amdgcn_s_barrier();          // all waves done reading buf[cur]
        __builtin_amdgcn_sched_barrier(0);     // pin next stage's vmem below barrier
    }

    // epilogue: per-wave transpose via sO (aliases buffer 0; safe: last-iter
    // vmcnt(0) drained all staging, loop-end barrier passed, region wave-local;
    // compiler inserts lgkmcnt for the sO write->read dependency).
    char* sO = smem + wave * 4096;  // [16][128] bf16 per wave
#pragma unroll
    for (int mg = 0; mg < 2; ++mg) {
        float inv = 1.0f / l_i[mg];
#pragma unroll
        for (int nt = 0; nt < 8; ++nt) {
            union { short h[4]; uint2 v; } u;
            __hip_bfloat16* hh = (__hip_bfloat16*)u.h;
            hh[0] = __float2bfloat16(o_acc[mg][nt][0] * inv);
            hh[1] = __float2bfloat16(o_acc[mg][nt][1] * inv);
            hh[2] = __float2bfloat16(o_acc[mg][nt][2] * inv);
            hh[3] = __float2bfloat16(o_acc[mg][nt][3] * inv);
            int pc = (2 * nt + (quad >> 1)) ^ ((l16 >> 1) & 3);
            *(uint2*)(sO + l16 * 256 + pc * 16 + (quad & 1) * 8) = u.v;
        }
#pragma unroll
        for (int cc = 0; cc < 4; ++cc) {
            int qr  = lane >> 2;            // 0..15
            int c16 = (lane & 3) + cc * 4;  // logical 16B chunk
            int pc  = c16 ^ ((qr >> 1) & 3);
            short8 ov = *(const short8*)(sO + qr * 256 + pc * 16);
            int s = q0 + wave * 32 + mg * 16 + qr;
            *(short8*)(Qio + (size_t)(s * 4 + b) * 2048 + nh * 128 + c16 * 8) = ov;
        }
        // no barrier needed between mg passes: each wave reads only its own sO
        // region, and intra-wave LDS ops are ordered by lgkmcnt.
    }
}

// ---------------------------------------------------------------- launch
extern "C" void kernel_launch(void* const* d_in, const int* in_sizes, int n_in,
                              void* d_out, int out_size, void* d_ws, size_t ws_size,
                              hipStream_t stream) {
    const float* x  = (const float*)d_in[0];
    const float* wq = (const float*)d_in[1];
    const float* bq = (const float*)d_in[2];
    const float* wk = (const float*)d_in[3];
    const float* bk = (const float*)d_in[4];
    const float* wv = (const float*)d_in[5];
    const float* bv = (const float*)d_in[6];
    const float* wd = (const float*)d_in[7];
    const float* bd = (const float*)d_in[8];
    // d_in[9] = start_pos: unused (reference recomputes t=arange(seq))

    const size_t TH = (size_t)8192 * 2048;  // 16.7M elems
    const size_t HH = (size_t)2048 * 2048;  // 4M elems
    dim3 gg(64, 16);

    if (ws_size >= (136ull << 20)) {
        // spacious: pre-convert to bf16, all GEMMs fully async (m97-style)
        __hip_bfloat16* xb  = (__hip_bfloat16*)d_ws;
        __hip_bfloat16* Qb  = xb + TH;
        __hip_bfloat16* Kb  = Qb + TH;
        __hip_bfloat16* Vtb = Kb + TH;
        __hip_bfloat16* wb  = Vtb + TH;  // reused per GEMM

        cvt_bf16<<<(int)(TH / 1024), 256, 0, stream>>>(x, xb, (int)TH);
        cvt_bf16<<<(int)(HH / 1024), 256, 0, stream>>>(wq, wb, (int)HH);
        gemm_k<1, 1, 1><<<gg, 256, 0, stream>>>(xb, wb, bq, Qb, 8192, 2048, 2048);
        cvt_bf16<<<(int)(HH / 1024), 256, 0, stream>>>(wk, wb, (int)HH);
        gemm_k<1, 1, 1><<<gg, 256, 0, stream>>>(xb, wb, bk, Kb, 8192, 2048, 2048);
        cvt_bf16<<<(int)(HH / 1024), 256, 0, stream>>>(wv, wb, (int)HH);
        gemm_k<1, 1, 2><<<gg, 256, 0, stream>>>(xb, wb, bv, Vtb, 8192, 2048, 2048);

        rope_kernel<<<32768, 256, 0, stream>>>(Qb, Kb);
        attn_kernel<<<dim3(64, 16), 256, 0, stream>>>(Qb, Kb, Vtb);

        cvt_bf16<<<(int)(HH / 1024), 256, 0, stream>>>(wd, wb, (int)HH);
        gemm_k<1, 1, 0><<<gg, 256, 0, stream>>>(Qb, wb, bd, d_out, 8192, 2048, 2048);
    } else {
        // tight (96 MiB total scratch): Q in ws; K,Vt inside d_out
        __hip_bfloat16* Qb = (__hip_bfloat16*)d_ws;
        __hip_bfloat16* Kb = (__hip_bfloat16*)d_out;
        __hip_bfloat16* Vt = (__hip_bfloat16*)d_out + TH;

        gemm_k<0, 0, 1><<<gg, 256, 0, stream>>>(x, wq, bq, Qb, 8192, 2048, 2048);
        gemm_k<0, 0, 1><<<gg, 256, 0, stream>>>(x, wk, bk, Kb, 8192, 2048, 2048);
        gemm_k<0, 0, 2><<<gg, 256, 0, stream>>>(x, wv, bv, Vt, 8192, 2048, 2048);

        rope_kernel<<<32768, 256, 0, stream>>>(Qb, Kb);
        attn_kernel<<<dim3(64, 16), 256, 0, stream>>>(Qb, Kb, Vt);

        // final projection: A (attn out) is bf16 -> async; B stays f32 sync-cvt
        gemm_k<1, 0, 0><<<gg, 256, 0, stream>>>(Qb, wd, bd, d_out, 8192, 2048, 2048);
    }
    (void)in_sizes; (void)n_in; (void)out_size; (void)ws_size;
}